// Round 6
// baseline (329.726 us; speedup 1.0000x reference)
//
#include <hip/hip_runtime.h>

#define N_NODES 50000
#define E_EDGES 800000
#define M_ROWS  12500
#define IN_DIM  256
#define HID     128
#define OUT_DIM 64
#define EPS     1e-5f
#define SLOPE   0.1f
#define SB_BITS 9
#define SB_SIZE 512
#define NSB     196         // ceil(2N / 512) super-buckets
#define SB_CAP  (12 * 1024) // mean 8192, sigma~90 -> 45 sigma; fixed inputs safe

typedef unsigned short u16;
typedef unsigned int u32;
typedef __attribute__((ext_vector_type(8))) short short8;
typedef __attribute__((ext_vector_type(4))) float f32x4;

__device__ __forceinline__ float leaky_f(float x) { return x >= 0.f ? x : SLOPE * x; }

__device__ __forceinline__ u16 f2bf(float f) {
  u32 x = __float_as_uint(f);
  return (u16)((x + 0x7fffu + ((x >> 16) & 1u)) >> 16);
}
__device__ __forceinline__ float bf2f(u16 u) { return __uint_as_float((u32)u << 16); }
__device__ __forceinline__ float bf2f_lo(u32 v) { return __uint_as_float(v << 16); }
__device__ __forceinline__ float bf2f_hi(u32 v) { return __uint_as_float(v & 0xffff0000u); }

// Async global->LDS, 16B per lane. LDS dest is WAVE-UNIFORM base + lane*16
// (HW scatter); global src is per-lane. Cannot be sunk by the scheduler
// (no VGPR destination) -- this is the fix for R1/R4's defeated prefetch.
__device__ __forceinline__ void gl_lds16(const void* g, void* l) {
  __builtin_amdgcn_global_load_lds(
      (const __attribute__((address_space(1))) u32*)g,
      (__attribute__((address_space(3))) u32*)l, 16, 0, 0);
}

struct GArgs {
  const void* A1[2];
  const void* A2[2];
  const u16* Bt[2];
  const float* bias[2];
  u16* Cb[2];
  float* bnsum[2];
  float* bnss[2];
  const int* seg[2];
  const int* cnt[2];
  float* y[2];
};

struct EdgeArgs {
  const int* src[2];
  const int* dst[2];
  const int* seg[2];
};

struct CvtArgs {
  const float* W[12];
  u16* Bt;
};

// ---------------------------------------------------------------------------
// global_load_lds streaming MFMA GEMM. 512 threads = 8 waves; wave owns a
// 16-row x BN strip and stages ITS OWN 16 A-rows (in-place safety preserved).
// Prologue: issue all global_load_lds (A tile + B tile, ~128KB in flight per
// block) -> ONE __syncthreads (vmcnt drain) -> pure swizzled ds_read + MFMA.
// XOR swizzle byte^=(row&7)<<4 applied to the GLOBAL SOURCE at stage time and
// the ds_read address at compute time (linear LDS dest, rule: both sides or
// neither) -> conflict-free b128 reads.
// MODE 0 ENCODE: A = f32 staged in 2 half-K chunks of 64KB (LDS budget);
//                convert f32->bf16 at ds_read; BN col stats LDS-reduced.
// MODE 1 LAYER : A1,A2 = bf16 (K split 128+128); C = bf16 leaky (in-place
//                safe: waves only write/stage rows they own).
// MODE 2 POOL  : A1 = bf16; no act; atomicAdd (v*w) into y[seg[row]][col].
// ---------------------------------------------------------------------------
template <int BN, int MODE, int KTOT>
__global__ __launch_bounds__(512) void gemm_stream(GArgs ga, int nrows) {
  constexpr int NI = BN / 16;
  constexpr int KT = KTOT / 32;
  constexpr int RB = KTOT * 2;                  // bf16 row bytes (A for MODE1/2, B all modes)
  constexpr int A_BYTES = (MODE == 0) ? 65536 : 128 * RB;
  constexpr int B_BYTES = BN * KTOT * 2;
  constexpr int SM = A_BYTES + B_BYTES + ((MODE == 0) ? 1024 : 0);
  constexpr int BI = B_BYTES / 1024 / 8;        // B stage insts per wave
  constexpr int RBSH = (RB == 512) ? 9 : 8;
  __shared__ __align__(16) char smem[SM];
  char* As = smem;
  char* Bs = smem + A_BYTES;
  float* redS = (float*)(smem + A_BYTES + B_BYTES);
  float* redQ = redS + 128;

  const int pb = blockIdx.y;
  const int t = threadIdx.x;
  const int w = t >> 6, lane = t & 63;
  const int laneM = lane & 15, kg = lane >> 4;
  const int m0 = blockIdx.x * 128;

  const u16* Bt = ga.Bt[pb];
  const char* Btb = (const char*)Bt;
  const float* bias = ga.bias[pb];

  // ---- stage A (wave's own 16 rows) ----
  if constexpr (MODE == 0) {
    const char* featb = (const char*)ga.A1[pb];  // f32, 1024B/row
#pragma unroll
    for (int j = 0; j < 8; j++) {                // half-0: 64KB = 8 insts/wave
      int inst = w * 8 + j;
      int L = inst * 1024 + lane * 16;
      int row = L >> 9, kb = L & 511;
      int grA = m0 + row; if (grA >= nrows) grA = nrows - 1;
      int kbs = kb ^ ((row & 7) << 4);
      gl_lds16(featb + (size_t)grA * 1024 + kbs, As + inst * 1024);
    }
  } else if constexpr (MODE == 1) {
    const char* A1b = (const char*)ga.A1[pb];    // bf16, 256B/row
    const char* A2b = (const char*)ga.A2[pb];
#pragma unroll
    for (int j = 0; j < 8; j++) {                // 64KB = 8 insts/wave
      int inst = w * 8 + j;
      int L = inst * 1024 + lane * 16;
      int row = L >> 9, kb = L & 511;
      int grA = m0 + row; if (grA >= nrows) grA = nrows - 1;
      int kbs = kb ^ ((row & 7) << 4);           // stays within its 256B half
      const char* src = (kbs < 256) ? (A1b + (size_t)grA * 256 + kbs)
                                    : (A2b + (size_t)grA * 256 + (kbs - 256));
      gl_lds16(src, As + inst * 1024);
    }
  } else {
    const char* A1b = (const char*)ga.A1[pb];    // bf16, 256B/row
#pragma unroll
    for (int j = 0; j < 4; j++) {                // 32KB = 4 insts/wave
      int inst = w * 4 + j;
      int L = inst * 1024 + lane * 16;
      int row = L >> 8, kb = L & 255;
      int grA = m0 + row; if (grA >= nrows) grA = nrows - 1;
      int kbs = kb ^ ((row & 7) << 4);
      gl_lds16(A1b + (size_t)grA * 256 + kbs, As + inst * 1024);
    }
  }
  // ---- stage B (cooperative, L2-resident Bt) ----
#pragma unroll
  for (int j = 0; j < BI; j++) {
    int inst = w * BI + j;
    int L = inst * 1024 + lane * 16;
    int n = L >> RBSH, kb = L & (RB - 1);
    int kbs = kb ^ ((n & 7) << 4);
    gl_lds16(Btb + (size_t)n * RB + kbs, Bs + inst * 1024);
  }
  if constexpr (MODE == 0) {
    if (t < 128) { redS[t] = 0.f; redQ[t] = 0.f; }
  }
  __syncthreads();  // single drain: vmcnt(0) + barrier

  // ---- steady state: swizzled ds_read + MFMA ----
  const int arow = w * 16 + laneM;
  const int swzr = (arow & 7) << 4;
  const char* Arow = As + (size_t)arow * ((MODE == 0) ? 512 : RB);

  f32x4 acc[NI];
#pragma unroll
  for (int ni = 0; ni < NI; ni++) acc[ni] = (f32x4){0.f, 0.f, 0.f, 0.f};

  if constexpr (MODE == 0) {
    const char* featb = (const char*)ga.A1[pb];
#pragma unroll
    for (int h = 0; h < 2; h++) {
      if (h == 1) {
        __syncthreads();  // all waves done reading half-0 A
#pragma unroll
        for (int j = 0; j < 8; j++) {            // stage half-1 (own rows)
          int inst = w * 8 + j;
          int L = inst * 1024 + lane * 16;
          int row = L >> 9, kb = L & 511;
          int grA = m0 + row; if (grA >= nrows) grA = nrows - 1;
          int kbs = kb ^ ((row & 7) << 4);
          gl_lds16(featb + (size_t)grA * 1024 + 512 + kbs, As + inst * 1024);
        }
        __syncthreads();
      }
#pragma unroll
      for (int ktl = 0; ktl < 4; ktl++) {
        int fb0 = ktl * 128 + kg * 32;
        float4 lo = *(const float4*)(Arow + (fb0 ^ swzr));
        float4 hi = *(const float4*)(Arow + ((fb0 + 16) ^ swzr));
        short8 a;
        a[0] = (short)f2bf(lo.x); a[1] = (short)f2bf(lo.y);
        a[2] = (short)f2bf(lo.z); a[3] = (short)f2bf(lo.w);
        a[4] = (short)f2bf(hi.x); a[5] = (short)f2bf(hi.y);
        a[6] = (short)f2bf(hi.z); a[7] = (short)f2bf(hi.w);
        int fb = (h * 4 + ktl) * 64 + kg * 16;
#pragma unroll
        for (int ni = 0; ni < NI; ni++) {
          int n = ni * 16 + laneM;
          short8 b = *(const short8*)(Bs + (size_t)n * RB + (fb ^ ((n & 7) << 4)));
          acc[ni] = __builtin_amdgcn_mfma_f32_16x16x32_bf16(a, b, acc[ni], 0, 0, 0);
        }
      }
    }
  } else {
#pragma unroll
    for (int kt = 0; kt < KT; kt++) {
      int fb = kt * 64 + kg * 16;
      short8 a = *(const short8*)(Arow + (fb ^ swzr));
#pragma unroll
      for (int ni = 0; ni < NI; ni++) {
        int n = ni * 16 + laneM;
        short8 b = *(const short8*)(Bs + (size_t)n * RB + (fb ^ ((n & 7) << 4)));
        acc[ni] = __builtin_amdgcn_mfma_f32_16x16x32_bf16(a, b, acc[ni], 0, 0, 0);
      }
    }
  }

  // ---- epilogue ----
  float bcol[NI];
#pragma unroll
  for (int ni = 0; ni < NI; ni++) bcol[ni] = bias[ni * 16 + laneM];

  float ssum[NI], ssq[NI];
#pragma unroll
  for (int ni = 0; ni < NI; ni++) { ssum[ni] = 0.f; ssq[ni] = 0.f; }

#pragma unroll
  for (int r = 0; r < 4; r++) {
    int gr = m0 + w * 16 + kg * 4 + r;
    if (gr >= nrows) continue;
    float pw = 0.f;
    int sI = 0;
    if constexpr (MODE == 2) {
      sI = ga.seg[pb][gr];
      int cv = ga.cnt[pb][sI];
      pw = 1.f / (float)(cv > 1 ? cv : 1);
    }
#pragma unroll
    for (int ni = 0; ni < NI; ni++) {
      int col = ni * 16 + laneM;
      float v = acc[ni][r] + bcol[ni];
      if constexpr (MODE == 0) {
        v = leaky_f(v);
        ga.Cb[pb][(size_t)gr * BN + col] = f2bf(v);
        ssum[ni] += v;
        ssq[ni] += v * v;
      } else if constexpr (MODE == 1) {
        v = leaky_f(v);
        ga.Cb[pb][(size_t)gr * BN + col] = f2bf(v);
      } else {
        atomicAdd(&ga.y[pb][(size_t)sI * OUT_DIM + col], v * pw);
      }
    }
  }

  if constexpr (MODE == 0) {
#pragma unroll
    for (int ni = 0; ni < NI; ni++) {
      float a = ssum[ni], b = ssq[ni];
      a += __shfl_xor(a, 16); a += __shfl_xor(a, 32);
      b += __shfl_xor(b, 16); b += __shfl_xor(b, 32);
      if (kg == 0) {
        atomicAdd(&redS[ni * 16 + laneM], a);
        atomicAdd(&redQ[ni * 16 + laneM], b);
      }
    }
    __syncthreads();
    if (t < 128) {
      atomicAdd(&ga.bnsum[pb][t], redS[t]);
      atomicAdd(&ga.bnss[pb][t], redQ[t]);
    }
  }
}

// Weights -> bf16 transposed Bt[n][k]; SKIPS Bt0 (folded later with BN affine).
__global__ __launch_bounds__(256) void cvt_weightsA(CvtArgs a) {
  int i = blockIdx.x * 256 + threadIdx.x;
  if (i >= 2 * 106496) return;
  int p = i >= 106496;
  int j = i - p * 106496;
  const float* const* W = a.W + p * 6;
  u16* out = a.Bt + (size_t)p * 106496;
  if (j < 32768) {
    int n = j >> 8, k = j & 255;
    out[j] = f2bf(W[0][k * 128 + n]);
  } else if (j < 65536) {
    return;
  } else if (j < 98304) {
    int q = j - 65536, n = q >> 8, k = q & 255;
    out[j] = f2bf(k < 128 ? W[3][k * 128 + n] : W[4][(k - 128) * 128 + n]);
  } else {
    int q = j - 98304, n = q >> 7, k = q & 127;
    out[j] = f2bf(W[5][k * 64 + n]);
  }
}

// abc layout: a[256] | c[256] | nc[256] | bias0p[256]
__global__ void bn_final(const float* __restrict__ bnstat,
                         const float* __restrict__ g0, const float* __restrict__ b0,
                         const float* __restrict__ g1, const float* __restrict__ b1,
                         float* __restrict__ abc) {
  int t = threadIdx.x;  // 256
  int p = t >> 7, cix = t & 127;
  const float* bs = bnstat + p * 256;
  float mu = bs[cix] * (1.f / N_NODES);
  float var = bs[128 + cix] * (1.f / N_NODES) - mu * mu;
  float rs = rsqrtf(var + EPS);
  const float* g = p ? g1 : g0;
  const float* b = p ? b1 : b0;
  float av = g[cix] * rs;
  float cv = b[cix] - mu * av;
  abc[t] = av;
  abc[256 + t] = cv;
  abc[512 + t] = (av != 0.f) ? (-cv / av) : 0.f;
}

// Fold BN affine into layer-0 weights.
__global__ __launch_bounds__(256) void cvt_fold(
    const float* __restrict__ Wl0_0, const float* __restrict__ Wr0_0,
    const float* __restrict__ Wl0_1, const float* __restrict__ Wr0_1,
    const float* __restrict__ b0_0, const float* __restrict__ b0_1,
    float* __restrict__ abc, u16* __restrict__ BtAll) {
  int i = blockIdx.x * 256 + threadIdx.x;
  if (i < 65536) {
    int p = i >> 15, q = i & 32767;
    int n = q >> 8, k = q & 255;
    const float* Wl = p ? Wl0_1 : Wl0_0;
    const float* Wr = p ? Wr0_1 : Wr0_0;
    float wv = (k < 128) ? Wl[k * 128 + n] : Wr[(k - 128) * 128 + n];
    float av = abc[p * 128 + (k & 127)];
    BtAll[(size_t)p * 106496 + 32768 + q] = f2bf(wv * av);
  } else if (i < 65536 + 256) {
    int j = i - 65536;
    int p = j >> 7, n = j & 127;
    const float* Wl = p ? Wl0_1 : Wl0_0;
    const float* Wr = p ? Wr0_1 : Wr0_0;
    const float* c = abc + 256 + p * 128;
    float s = (p ? b0_1 : b0_0)[n];
    for (int k = 0; k < 128; k++) s += c[k] * (Wl[k * 128 + n] + Wr[k * 128 + n]);
    abc[768 + j] = s;
  }
}

// pooling counts
__global__ void cnt_count(EdgeArgs ea, int* __restrict__ cnt) {
  int i = blockIdx.x * blockDim.x + threadIdx.x;
  if (i < 2 * N_NODES) {
    int p = i >= N_NODES;
    int k = i - p * N_NODES;
    atomicAdd(&cnt[p * M_ROWS + ea.seg[p][k]], 1);
  }
}

// --------- Phase A: partition edges into NSB super-buckets ------------------
// packed: dst_local(9b) << 17 | src(16b). Tile = 2048 edges, block-local
// counting sort, wave-per-bucket chunk copy-out.
__global__ __launch_bounds__(256) void part_edges(EdgeArgs ea, u32* __restrict__ sbuf,
                                                  int* __restrict__ gcursor) {
  __shared__ u32 lpack[2048];
  __shared__ int hist[NSB], base[NSB], gbase[NSB], lofs[NSB];
  int t = threadIdx.x;
  int e0 = blockIdx.x * 2048;
  for (int i = t; i < NSB; i += 256) hist[i] = 0;
  __syncthreads();
  u32 myp[8];
  int myb[8];
#pragma unroll
  for (int q = 0; q < 8; q++) {
    int i = e0 + q * 256 + t;
    int b = -1;
    u32 pk = 0;
    if (i < 2 * E_EDGES) {
      int p = i >= E_EDGES;
      int j = i - p * E_EDGES;
      int d = p * N_NODES + ea.dst[p][j];
      int s = ea.src[p][j];
      b = d >> SB_BITS;
      pk = ((u32)(d & (SB_SIZE - 1)) << 17) | (u32)s;
      atomicAdd(&hist[b], 1);
    }
    myb[q] = b;
    myp[q] = pk;
  }
  __syncthreads();
  if (t == 0) {
    int acc = 0;
    for (int b = 0; b < NSB; b++) { base[b] = acc; acc += hist[b]; }
  }
  __syncthreads();
  for (int i = t; i < NSB; i += 256) {
    lofs[i] = 0;
    gbase[i] = atomicAdd(&gcursor[i], hist[i]);
  }
  __syncthreads();
#pragma unroll
  for (int q = 0; q < 8; q++) {
    if (myb[q] >= 0) {
      int pos = atomicAdd(&lofs[myb[q]], 1);
      lpack[base[myb[q]] + pos] = myp[q];
    }
  }
  __syncthreads();
  int wid = t >> 6, lane = t & 63;
  for (int b = wid; b < NSB; b += 4) {
    int n = hist[b], lb = base[b], gb = gbase[b];
    for (int k = lane; k < n; k += 64)
      sbuf[(size_t)b * SB_CAP + gb + k] = lpack[lb + k];
  }
}

// --------- Phase B: per-super-bucket CSR build (one block per bucket) -------
// 196 blocks x 512 threads; 512-node buckets -> ~8K edges/block.
__global__ __launch_bounds__(512) void build_csr(
    const u32* __restrict__ sbuf, const int* __restrict__ gtot,
    int* __restrict__ offs, float* __restrict__ dinv, u16* __restrict__ colu) {
  __shared__ int ldeg[SB_SIZE];
  __shared__ int lcur[SB_SIZE];
  __shared__ int wsum[8];
  __shared__ int sbase_s;
  int b = blockIdx.x, t = threadIdx.x;
  int lane = t & 63, wid = t >> 6;
  ldeg[t] = 0;
  if (t < 64) {
    // edge_base = sum of gtot[0..b) via 64-lane masked sum + butterfly
    int s = 0;
    for (int i = lane; i < b; i += 64) s += gtot[i];
#pragma unroll
    for (int off = 1; off < 64; off <<= 1) s += __shfl_xor(s, off, 64);
    if (lane == 0) sbase_s = s;
  }
  __syncthreads();
  const int cnt = gtot[b];
  const int edge_base = sbase_s;
  const int node0 = b << SB_BITS;
  int nend = 2 * N_NODES - node0;
  if (nend > SB_SIZE) nend = SB_SIZE;
  const u32* me = sbuf + (size_t)b * SB_CAP;
  for (int k = t; k < cnt; k += 512) atomicAdd(&ldeg[me[k] >> 17], 1);
  __syncthreads();
  // block scan over 512 (one node per thread)
  int d = ldeg[t];
  int incl = d;
#pragma unroll
  for (int off = 1; off < 64; off <<= 1) {
    int u = __shfl_up(incl, off, 64);
    if (lane >= off) incl += u;
  }
  if (lane == 63) wsum[wid] = incl;
  __syncthreads();
  if (t == 0) {
    int acc = 0;
#pragma unroll
    for (int i = 0; i < 8; i++) { int v = wsum[i]; wsum[i] = acc; acc += v; }
  }
  __syncthreads();
  int ex = wsum[wid] + incl - d;
  if (t < nend) {
    offs[node0 + t] = edge_base + ex;
    dinv[node0 + t] = d > 0 ? 1.f / (float)d : -1.f;
  }
  lcur[t] = ex;
  __syncthreads();
  for (int k = t; k < cnt; k += 512) {
    u32 v = me[k];
    int pos = atomicAdd(&lcur[v >> 17], 1);
    colu[edge_base + pos] = (u16)(v & 0xFFFFu);
  }
  if (b == 0 && t == 0) offs[2 * N_NODES] = 2 * E_EDGES;
}

// --------- mean-aggregate v2: 1 wave/node, 4 edge-groups x 16 col-lanes ----
// Lane loads uint4 (16B = 8 bf16 cols); main loop = 16 edges/iter -> 4
// independent gathers per lane in flight. dinv<0 marks deg==0 -> nc[col].
__global__ __launch_bounds__(256) void aggregate_bf16(
    const u16* __restrict__ h, const u16* __restrict__ colu,
    const int* __restrict__ offs, const float* __restrict__ dinv,
    const float* __restrict__ nc, u16* __restrict__ agg) {
  int gw = (blockIdx.x * 256 + threadIdx.x) >> 6;
  int lane = threadIdx.x & 63;
  if (gw >= 2 * N_NODES) return;
  int panel = gw >= N_NODES;
  const uint4* hp = (const uint4*)(h + (size_t)panel * N_NODES * 128);
  int grp = lane >> 4, li = lane & 15;
  int s = offs[gw], e = offs[gw + 1];
  float a[8];
#pragma unroll
  for (int k = 0; k < 8; k++) a[k] = 0.f;

  auto acc8 = [&](uint4 v) {
    a[0] += bf2f_lo(v.x); a[1] += bf2f_hi(v.x);
    a[2] += bf2f_lo(v.y); a[3] += bf2f_hi(v.y);
    a[4] += bf2f_lo(v.z); a[5] += bf2f_hi(v.z);
    a[6] += bf2f_lo(v.w); a[7] += bf2f_hi(v.w);
  };

  int j = s;
  for (; j + 16 <= e; j += 16) {
    int c0 = colu[j + grp];
    int c1 = colu[j + 4 + grp];
    int c2 = colu[j + 8 + grp];
    int c3 = colu[j + 12 + grp];
    uint4 v0 = hp[(size_t)c0 * 16 + li];
    uint4 v1 = hp[(size_t)c1 * 16 + li];
    uint4 v2 = hp[(size_t)c2 * 16 + li];
    uint4 v3 = hp[(size_t)c3 * 16 + li];
    acc8(v0); acc8(v1); acc8(v2); acc8(v3);
  }
  for (; j + 4 <= e; j += 4) {
    int c = colu[j + grp];
    uint4 v = hp[(size_t)c * 16 + li];
    acc8(v);
  }
  if (j + grp < e) {
    int c = colu[j + grp];
    uint4 v = hp[(size_t)c * 16 + li];
    acc8(v);
  }

#pragma unroll
  for (int k = 0; k < 8; k++) {
    a[k] += __shfl_xor(a[k], 16);
    a[k] += __shfl_xor(a[k], 32);
  }

  if (grp == 0) {
    float di = dinv[gw];
    float o[8];
    if (di < 0.f) {
      const float* np = nc + panel * 128 + li * 8;
#pragma unroll
      for (int k = 0; k < 8; k++) o[k] = np[k];
    } else {
#pragma unroll
      for (int k = 0; k < 8; k++) o[k] = a[k] * di;
    }
    uint4 ov;
    ov.x = ((u32)f2bf(o[1]) << 16) | (u32)f2bf(o[0]);
    ov.y = ((u32)f2bf(o[3]) << 16) | (u32)f2bf(o[2]);
    ov.z = ((u32)f2bf(o[5]) << 16) | (u32)f2bf(o[4]);
    ov.w = ((u32)f2bf(o[7]) << 16) | (u32)f2bf(o[6]);
    ((uint4*)agg)[(size_t)gw * 16 + li] = ov;
  }
}

__global__ __launch_bounds__(256) void mse_kernel(const float* __restrict__ yb,
                                                  const float* __restrict__ x0,
                                                  const float* __restrict__ x1,
                                                  float* __restrict__ acc) {
  __shared__ float ls[256];
  int pb = blockIdx.y;
  const float* y = yb + (size_t)pb * M_ROWS * OUT_DIM;
  const float* x = pb ? x1 : x0;
  float s = 0.f;
  for (int i = blockIdx.x * 256 + threadIdx.x; i < M_ROWS * OUT_DIM; i += gridDim.x * 256) {
    float d = y[i] - x[i];
    s += d * d;
  }
  ls[threadIdx.x] = s;
  __syncthreads();
  for (int o = 128; o > 0; o >>= 1) {
    if (threadIdx.x < o) ls[threadIdx.x] += ls[threadIdx.x + o];
    __syncthreads();
  }
  if (threadIdx.x == 0) atomicAdd(&acc[pb], ls[0]);
}

__global__ void finalize(const float* __restrict__ acc, float* __restrict__ out) {
  int t = threadIdx.x;
  if (t < 2) out[t] = acc[t] * (1.f / (float)(M_ROWS * OUT_DIM));
}

// ---------------------------------------------------------------------------
extern "C" void kernel_launch(void* const* d_in, const int* in_sizes, int n_in,
                              void* d_out, int out_size, void* d_ws, size_t ws_size,
                              hipStream_t stream) {
  (void)in_sizes; (void)n_in; (void)out_size; (void)ws_size;
  const float* feat[2] = {(const float*)d_in[0], (const float*)d_in[1]};
  const float* xmat[2] = {(const float*)d_in[2], (const float*)d_in[3]};
  const int* esrc[2] = {(const int*)d_in[4], (const int*)d_in[6]};
  const int* edst[2] = {(const int*)d_in[5], (const int*)d_in[7]};
  const int* aseg[2] = {(const int*)d_in[8], (const int*)d_in[9]};

  struct P {
    const float *W_mlp, *b_mlp, *bn_g, *bn_b, *Wl0, *Wr0, *b0, *Wl1, *Wr1, *b1, *Wp, *bp;
  } prm[2];
  for (int p = 0; p < 2; p++) {
    int b = 10 + 12 * p;
    prm[p] = {(const float*)d_in[b + 0], (const float*)d_in[b + 1],
              (const float*)d_in[b + 2], (const float*)d_in[b + 3],
              (const float*)d_in[b + 4], (const float*)d_in[b + 5],
              (const float*)d_in[b + 6], (const float*)d_in[b + 7],
              (const float*)d_in[b + 8], (const float*)d_in[b + 9],
              (const float*)d_in[b + 10], (const float*)d_in[b + 11]};
  }

  char* w = (char*)d_ws;
  auto carve = [&](size_t bytes) -> char* {
    char* r = w;
    w += (bytes + 255) & ~(size_t)255;
    return r;
  };
  // ---- zeroed region (single memset) ----
  char* zbase = w;
  int* gcursor = (int*)carve(NSB * 4);
  int* cnt    = (int*)carve((size_t)2 * M_ROWS * 4);
  float* bnstat = (float*)carve(2 * 256 * 4);
  float* lossacc = (float*)carve(64 * 4);
  float* zerobuf = (float*)carve(256 * 4);
  float* yb   = (float*)carve((size_t)2 * M_ROWS * OUT_DIM * 4);
  size_t zbytes = (size_t)(w - zbase);
  // ---- non-zeroed ----
  u16* hb   = (u16*)carve((size_t)2 * N_NODES * HID * 2);
  u16* aggb = (u16*)carve((size_t)2 * N_NODES * HID * 2);
  u32* sbuf = (u32*)aggb;  // aliased: sbuf (9.6MB) dead before first aggregate write
  float* dinv = (float*)carve((size_t)2 * N_NODES * 4);
  float* abc = (float*)carve(1024 * 4);  // a|c|nc|bias0p
  int* offs = (int*)carve((size_t)(2 * N_NODES + 1) * 4);
  u16* colu = (u16*)carve((size_t)2 * E_EDGES * 2);
  u16* BtAll = (u16*)carve((size_t)2 * 106496 * 2);

  const int TWO_N = 2 * N_NODES;

  EdgeArgs ea;
  for (int p = 0; p < 2; p++) { ea.src[p] = esrc[p]; ea.dst[p] = edst[p]; ea.seg[p] = aseg[p]; }

  CvtArgs ca;
  for (int p = 0; p < 2; p++) {
    ca.W[p * 6 + 0] = prm[p].W_mlp; ca.W[p * 6 + 1] = prm[p].Wl0;
    ca.W[p * 6 + 2] = prm[p].Wr0;   ca.W[p * 6 + 3] = prm[p].Wl1;
    ca.W[p * 6 + 4] = prm[p].Wr1;   ca.W[p * 6 + 5] = prm[p].Wp;
  }
  ca.Bt = BtAll;

  auto mkga = [&](int mode, int layer) {
    GArgs g{};
    for (int p = 0; p < 2; p++) {
      u16* hp = hb + (size_t)p * N_NODES * HID;
      const u16* btp = BtAll + (size_t)p * 106496;
      g.Cb[p] = hp;
      g.bnsum[p] = bnstat + p * 256;
      g.bnss[p] = bnstat + p * 256 + 128;
      g.seg[p] = aseg[p];
      g.cnt[p] = cnt + p * M_ROWS;
      g.y[p] = yb + (size_t)p * M_ROWS * OUT_DIM;
      if (mode == 0) {
        g.A1[p] = feat[p];
        g.Bt[p] = btp;
        g.bias[p] = prm[p].b_mlp;
      } else if (mode == 1) {
        g.A1[p] = hp;
        g.A2[p] = aggb + (size_t)p * N_NODES * HID;
        g.Bt[p] = btp + (layer ? 65536 : 32768);
        g.bias[p] = layer ? prm[p].b1 : (const float*)(abc + 768 + p * 128);
      } else {
        g.A1[p] = hp;
        g.Bt[p] = btp + 98304;
        g.bias[p] = prm[p].bp;
      }
    }
    return g;
  };

  const int GX = (N_NODES + 127) / 128;  // 391 blocks of 128 rows (8 waves x 16)

  hipMemsetAsync(zbase, 0, zbytes, stream);
  cvt_weightsA<<<(2 * 106496 + 255) / 256, 256, 0, stream>>>(ca);
  // edge partition + CSR build
  part_edges<<<(2 * E_EDGES + 2047) / 2048, 256, 0, stream>>>(ea, sbuf, gcursor);
  build_csr<<<NSB, 512, 0, stream>>>(sbuf, gcursor, offs, dinv, colu);
  cnt_count<<<(TWO_N + 255) / 256, 256, 0, stream>>>(ea, cnt);
  // encode (both panels) + BN stats; h stays PRE-BN (affine folded downstream)
  gemm_stream<128, 0, IN_DIM><<<dim3(GX, 2), 512, 0, stream>>>(mkga(0, 0), N_NODES);
  bn_final<<<1, 256, 0, stream>>>(bnstat, prm[0].bn_g, prm[0].bn_b,
                                  prm[1].bn_g, prm[1].bn_b, abc);
  cvt_fold<<<(65536 + 256 + 255) / 256, 256, 0, stream>>>(
      prm[0].Wl0, prm[0].Wr0, prm[1].Wl0, prm[1].Wr0, prm[0].b0, prm[1].b0,
      abc, BtAll);
  // SAGE layer 0 (raw h + BN-folded weights; deg==0 rows patched with nc)
  aggregate_bf16<<<(TWO_N * 64 + 255) / 256, 256, 0, stream>>>(
      hb, colu, offs, dinv, abc + 512, aggb);
  gemm_stream<128, 1, 2 * HID><<<dim3(GX, 2), 512, 0, stream>>>(mkga(1, 0), N_NODES);
  // SAGE layer 1 (in-place h; deg==0 rows -> 0)
  aggregate_bf16<<<(TWO_N * 64 + 255) / 256, 256, 0, stream>>>(
      hb, colu, offs, dinv, zerobuf, aggb);
  gemm_stream<128, 1, 2 * HID><<<dim3(GX, 2), 512, 0, stream>>>(mkga(1, 1), N_NODES);
  // projection + mean-pool
  gemm_stream<64, 2, HID><<<dim3(GX, 2), 512, 0, stream>>>(mkga(2, 0), N_NODES);
  mse_kernel<<<dim3(128, 2), 256, 0, stream>>>(yb, xmat[0], xmat[1], lossacc);
  finalize<<<1, 64, 0, stream>>>(lossacc, (float*)d_out);
}